// Round 15
// baseline (1481.359 us; speedup 1.0000x reference)
//
#include <hip/hip_runtime.h>
#include <hip/hip_fp16.h>

// ResidualVectorQuantizer: B=16, D=512, F=1500, Q=8, C=1024
#define B_ 16
#define D_ 512
#define F_ 1500
#define N_ (B_*F_)   // 24000
#define Q_ 8
#define C_ 1024

constexpr int NBLK  = (N_ + 255) / 256;   // 94
constexpr int MPAD = 24064;
constexpr int FB_  = (F_ + 31) / 32;      // 47
constexpr int TILES_ = B_ * 16 * FB_;     // 12032
constexpr int SBLK_ = N_ / 32;            // 750 stage blocks

typedef __attribute__((ext_vector_type(8))) short bf16x8;
typedef __attribute__((ext_vector_type(4))) short bf16x4;
typedef __attribute__((ext_vector_type(4))) float f32x4;

__device__ __forceinline__ short f2bf(float f) {
    unsigned u = __float_as_uint(f);
    u += 0x7FFFu + ((u >> 16) & 1u);
    return (short)(u >> 16);
}
__device__ __forceinline__ float h2f(unsigned short u) {
    __half_raw r; r.x = u; return __half2float(__half(r));
}
__device__ __forceinline__ unsigned short f2h(float f) {
    __half h = __float2half(f);
    return __half_as_ushort(h);
}

// ---------------- init: resT/resbf[b*F+f][d] = lat[b][d][f], float4 both sides ----------------
__global__ __launch_bounds__(256) void k_initT(const float* __restrict__ lat,
                                               float* __restrict__ resT,
                                               short* __restrict__ resbf) {
    __shared__ float tile[32][33];   // [d][f]
    const int t = threadIdx.x;
    const int row = t >> 3, q4 = t & 7;
    for (int bi = blockIdx.x; bi < TILES_; bi += 1024) {
        int fb = bi % FB_, rem = bi / FB_;
        int db = rem & 15, b = rem >> 4;
        int f0 = fb * 32, d0 = db * 32;
        {
            int fbase = f0 + 4 * q4;
            const float* lp = lat + ((size_t)b * D_ + d0 + row) * F_ + fbase;
            if (fbase + 3 < F_) {
                float4 v = *(const float4*)lp;
                tile[row][4*q4+0] = v.x; tile[row][4*q4+1] = v.y;
                tile[row][4*q4+2] = v.z; tile[row][4*q4+3] = v.w;
            } else {
#pragma unroll
                for (int k = 0; k < 4; ++k)
                    tile[row][4*q4+k] = (fbase + k < F_) ? lp[k] : 0.0f;
            }
        }
        __syncthreads();
        {
            int f = f0 + row;
            if (f < F_) {
                float4 v;
                v.x = tile[4*q4+0][row]; v.y = tile[4*q4+1][row];
                v.z = tile[4*q4+2][row]; v.w = tile[4*q4+3][row];
                size_t o = ((size_t)(b * F_ + f)) * D_ + d0 + 4 * q4;
                *(float4*)(resT + o) = v;
                bf16x4 s;
                s[0] = f2bf(v.x); s[1] = f2bf(v.y); s[2] = f2bf(v.z); s[3] = f2bf(v.w);
                *(bf16x4*)(resbf + o) = s;
            }
        }
        __syncthreads();
    }
}

// ---------------- cbh = bf16(cb) ----------------
__global__ void k_cbh(const float* __restrict__ cb, short* __restrict__ cbh) {
    for (int g = blockIdx.x * 256 + threadIdx.x; g < Q_ * C_ * D_ / 8; g += 512 * 256) {
        size_t base = (size_t)g * 8;
        float4 a = *(const float4*)(cb + base);
        float4 b = *(const float4*)(cb + base + 4);
        bf16x8 o;
        o[0]=f2bf(a.x); o[1]=f2bf(a.y); o[2]=f2bf(a.z); o[3]=f2bf(a.w);
        o[4]=f2bf(b.x); o[5]=f2bf(b.y); o[6]=f2bf(b.z); o[7]=f2bf(b.w);
        *(bf16x8*)(cbh + base) = o;
    }
}

// ---------------- H[q*C+c] = np.sum(cb*cb, axis=1), numpy pairwise fp32 (verified) ----------------
__global__ void k_cbnormP(const float* __restrict__ cb, float* __restrict__ Hq) {
#pragma clang fp contract(off)
    int wid = blockIdx.x * 256 + threadIdx.x;
    const float* p = cb + (size_t)wid * D_;
    float L[4];
#pragma unroll
    for (int l = 0; l < 4; ++l) {
        const float* pl = p + l * 128;
        float r[8];
#pragma unroll
        for (int j = 0; j < 8; ++j) { float x = pl[j]; r[j] = x * x; }
        for (int i = 8; i < 128; i += 8) {
#pragma unroll
            for (int j = 0; j < 8; ++j) { float x = pl[i + j]; r[j] = r[j] + x * x; }
        }
        L[l] = ((r[0] + r[1]) + (r[2] + r[3])) + ((r[4] + r[5]) + (r[6] + r[7]));
    }
    Hq[wid] = (L[0] + L[1]) + (L[2] + L[3]);
}

// ---------------- initial S partials (verified chain) ----------------
__global__ void k_rownorm4(const float* __restrict__ resT, float* __restrict__ Sp) {
#pragma clang fp contract(off)
    int n = blockIdx.x * 256 + threadIdx.x;
    if (n >= N_) return;
#pragma unroll
    for (int l = 0; l < 4; ++l) {
        const float* p = resT + (size_t)n * D_ + l * 128;
        float r[8];
#pragma unroll
        for (int j = 0; j < 8; ++j) { float x = p[j]; r[j] = x * x; }
        for (int i = 8; i < 128; i += 8) {
#pragma unroll
            for (int j = 0; j < 8; ++j) { float x = p[i + j]; r[j] = r[j] + x * x; }
        }
        Sp[(size_t)l * N_ + n] = ((r[0] + r[1]) + (r[2] + r[3])) + ((r[4] + r[5]) + (r[6] + r[7]));
    }
}

// ---------------- fused stage: MFMA screen + collect + exact rescore + residual update ----------------
// block = 32 rows x all 1024 cols; 750 blocks; update is block-local (rows owned by block).
#define LSTR 80
__global__ __launch_bounds__(256) void k_stage(
        const short* __restrict__ cbh, float* __restrict__ resT,
        short* __restrict__ resbf, const float* __restrict__ cb,
        const float* __restrict__ Hq, float* __restrict__ Sp,
        int* __restrict__ codes, double* __restrict__ part, int q) {
#pragma clang fp contract(off)
    __shared__ short xh[32 * LSTR];
    __shared__ short ch[128 * LSTR];
    __shared__ float smin[32][2];
    __shared__ float bminG[32];
    __shared__ unsigned lcnt[32];
    __shared__ unsigned slots[32][16];
    __shared__ unsigned witems[512];
    __shared__ unsigned long long rkeyL[32];
    __shared__ int fbrows[32];
    __shared__ int codeL[32];
    __shared__ unsigned wcnt_s, fbcnt_s;

    const int t = threadIdx.x, l = t & 63, w = t >> 6;
    const int wr = w >> 1, wc = w & 1;
    const int n0 = blockIdx.x * 32;
    const short* cbhq = cbh + (size_t)q * C_ * D_;
    const float* Hqq = Hq + (size_t)q * C_;
    const float* cbq = cb + (size_t)q * ((size_t)C_ * D_);

    if (t < 32) { bminG[t] = 3.4e38f; lcnt[t] = 0; rkeyL[t] = ~0ull; }
    if (t == 0) { wcnt_s = 0; fbcnt_s = 0; }

    for (int c0 = 0; c0 < C_; c0 += 128) {
        f32x4 acc[4];
#pragma unroll
        for (int j = 0; j < 4; ++j) { acc[j][0]=0.f; acc[j][1]=0.f; acc[j][2]=0.f; acc[j][3]=0.f; }

        for (int kc = 0; kc < D_; kc += 64) {
            __syncthreads();
            {   // stage X: 32 rows x 64 d (1 vec8/thread)
                int nn = t >> 3, d8 = t & 7;
                *(bf16x8*)(&xh[nn * LSTR + d8 * 8]) =
                    *(const bf16x8*)(resbf + (size_t)(n0 + nn) * D_ + kc + d8 * 8);
            }
#pragma unroll
            for (int p = 0; p < 4; ++p) {   // stage C: 128 rows x 64 d
                int idx = p * 256 + t;
                int cr = idx >> 3, d8 = idx & 7;
                *(bf16x8*)(&ch[cr * LSTR + d8 * 8]) =
                    *(const bf16x8*)(cbhq + (size_t)(c0 + cr) * D_ + kc + d8 * 8);
            }
            __syncthreads();

#pragma unroll
            for (int kf = 0; kf < 2; ++kf) {
                const int ko = kf * 32 + (l >> 4) * 8;
                bf16x8 ah = *(const bf16x8*)(&xh[(wr * 16 + (l & 15)) * LSTR + ko]);
                bf16x8 bh[4];
#pragma unroll
                for (int j = 0; j < 4; ++j)
                    bh[j] = *(const bf16x8*)(&ch[(wc * 64 + j * 16 + (l & 15)) * LSTR + ko]);
#pragma unroll
                for (int j = 0; j < 4; ++j)
                    acc[j] = __builtin_amdgcn_mfma_f32_16x16x32_bf16(ah, bh[j], acc[j], 0, 0, 0);
            }
        }

        float hv[4];
#pragma unroll
        for (int j = 0; j < 4; ++j) hv[j] = Hqq[c0 + wc * 64 + j * 16 + (l & 15)];

        // strip row minima
#pragma unroll
        for (int r = 0; r < 4; ++r) {
            float vm = hv[0] - 2.0f * acc[0][r];
#pragma unroll
            for (int j = 1; j < 4; ++j) vm = fminf(vm, hv[j] - 2.0f * acc[j][r]);
            vm = fminf(vm, __shfl_xor(vm, 1, 64));
            vm = fminf(vm, __shfl_xor(vm, 2, 64));
            vm = fminf(vm, __shfl_xor(vm, 4, 64));
            vm = fminf(vm, __shfl_xor(vm, 8, 64));
            if ((l & 15) == 0) smin[wr * 16 + (l >> 4) * 4 + r][wc] = vm;
        }
        __syncthreads();
        if (t < 32) bminG[t] = fminf(bminG[t], fminf(smin[t][0], smin[t][1]));
        __syncthreads();
        // emit candidates within running-min + 1.6e-3 (superset of decision set)
#pragma unroll
        for (int j = 0; j < 4; ++j)
#pragma unroll
            for (int r = 0; r < 4; ++r) {
                int row = wr * 16 + (l >> 4) * 4 + r;
                float v = hv[j] - 2.0f * acc[j][r];
                if (v <= bminG[row] + 1.6e-3f) {
                    unsigned pos = atomicAdd(&lcnt[row], 1u);
                    if (pos < 16) {
                        unsigned c = (unsigned)(c0 + wc * 64 + j * 16 + (l & 15));
                        slots[row][pos] = ((unsigned)f2h(v) << 16) | c;
                    }
                }
            }
    }
    __syncthreads();

    // finalize rows
    if (t < 32) {
        float thr = bminG[t] + 1.5e-3f;
        unsigned lc = lcnt[t];
        if (lc > 16u) {
            unsigned fp = atomicAdd(&fbcnt_s, 1u);
            fbrows[fp] = t;
        } else {
            int cnt = 0, c1 = -1;
            for (unsigned s = 0; s < lc; ++s) {
                unsigned e = slots[t][s];
                if (h2f((unsigned short)(e >> 16)) <= thr) { ++cnt; if (cnt == 1) c1 = (int)(e & 0x3FFu); }
            }
            if (cnt == 1) {
                codeL[t] = c1;
            } else {
                codeL[t] = -1;
                for (unsigned s = 0; s < lc; ++s) {
                    unsigned e = slots[t][s];
                    if (h2f((unsigned short)(e >> 16)) <= thr) {
                        unsigned pos = atomicAdd(&wcnt_s, 1u);
                        witems[pos] = ((unsigned)t << 10) | (e & 0x3FFu);
                    }
                }
            }
        }
    }
    __syncthreads();

    // dense exact-chain rescore (verified chain + lex tie)
    {
        unsigned wn = wcnt_s;
        for (unsigned i = t; i < wn; i += 256) {
            unsigned e = witems[i];
            int lr = (int)(e >> 10), c = (int)(e & 0x3FFu);
            int n = n0 + lr;
            float S = (Sp[n] + Sp[N_ + n]) + (Sp[2 * N_ + n] + Sp[3 * N_ + n]);
            const float* xr = resT + (size_t)n * D_;
            const float* cr = cbq + (size_t)c * D_;
            float A = 0.0f;
#pragma unroll 8
            for (int d = 0; d < D_; ++d) A = fmaf(xr[d], cr[d], A);
            float v = (S - 2.0f * A) + Hqq[c];
            unsigned long long key = ((unsigned long long)__float_as_uint(v) << 32) | (unsigned)c;
            atomicMin(&rkeyL[lr], key);
        }
    }
    __syncthreads();
    if (t < 32 && codeL[t] < 0) codeL[t] = (int)(rkeyL[t] & 0x3FFull);

    // rare full-row fallback (wave per row)
    {
        unsigned fn = fbcnt_s;
        for (unsigned fi = w; fi < fn; fi += 4) {
            int lr = fbrows[fi];
            int n = n0 + lr;
            float S = (Sp[n] + Sp[N_ + n]) + (Sp[2 * N_ + n] + Sp[3 * N_ + n]);
            const float4* xr4 = (const float4*)(resT + (size_t)n * D_);
            float mn = 3.4e38f;
            for (int rep = 0; rep < 16; ++rep) {
                int c = l + rep * 64;
                const float4* cr4 = (const float4*)(cbq + (size_t)c * D_);
                float a0 = 0.f, a1 = 0.f, a2 = 0.f, a3 = 0.f;
#pragma unroll 4
                for (int d4 = 0; d4 < 128; ++d4) {
                    float4 xv = xr4[d4], cv = cr4[d4];
                    a0 = fmaf(xv.x, cv.x, a0); a1 = fmaf(xv.y, cv.y, a1);
                    a2 = fmaf(xv.z, cv.z, a2); a3 = fmaf(xv.w, cv.w, a3);
                }
                float v = (S - 2.0f * ((a0 + a1) + (a2 + a3))) + Hqq[c];
                mn = fminf(mn, v);
            }
            for (int off = 32; off; off >>= 1) mn = fminf(mn, __shfl_xor(mn, off, 64));
            const float thr2 = mn + 6e-4f;
            float bv = 3.4e38f; int bc = 0x7fffffff;
            const float* xr = resT + (size_t)n * D_;
            for (int rep = 0; rep < 16; ++rep) {
                int c = l + rep * 64;
                const float4* cr4 = (const float4*)(cbq + (size_t)c * D_);
                float a0 = 0.f, a1 = 0.f, a2 = 0.f, a3 = 0.f;
#pragma unroll 4
                for (int d4 = 0; d4 < 128; ++d4) {
                    float4 xv = xr4[d4], cv = cr4[d4];
                    a0 = fmaf(xv.x, cv.x, a0); a1 = fmaf(xv.y, cv.y, a1);
                    a2 = fmaf(xv.z, cv.z, a2); a3 = fmaf(xv.w, cv.w, a3);
                }
                float vap = (S - 2.0f * ((a0 + a1) + (a2 + a3))) + Hqq[c];
                if (vap <= thr2) {
                    const float* cr = cbq + (size_t)c * D_;
                    float A = 0.0f;
#pragma unroll 8
                    for (int d = 0; d < D_; ++d) A = fmaf(xr[d], cr[d], A);
                    float v = (S - 2.0f * A) + Hqq[c];
                    if (v < bv || (v == bv && c < bc)) { bv = v; bc = c; }
                }
            }
            for (int off = 32; off; off >>= 1) {
                float ov = __shfl_xor(bv, off, 64);
                int oc = __shfl_xor(bc, off, 64);
                if (ov < bv || (ov == bv && oc < bc)) { bv = ov; bc = oc; }
            }
            if (l == 0) codeL[lr] = bc;
        }
    }
    __syncthreads();
    if (t < 32) codes[(size_t)q * N_ + n0 + t] = codeL[t];

    // ---- fused residual update (verified k_upd chain), rows owned by this block ----
    float L = 0.0f;
    if (t < 128) {
        int lr = t >> 2, seg = t & 3;
        int n = n0 + lr;
        int idx = codeL[lr];
        const float4* cr4 = (const float4*)(cb + ((size_t)q * C_ + idx) * D_ + seg * 128);
        float4* rp4 = (float4*)(resT + (size_t)n * D_ + seg * 128);
        short* rb = resbf + (size_t)n * D_ + seg * 128;
        float r8[8];
#pragma unroll
        for (int k = 0; k < 16; ++k) {
            float4 a = rp4[2*k], b = rp4[2*k+1];
            float4 ca = cr4[2*k], cb2 = cr4[2*k+1];
            float v0 = a.x - ca.x, v1 = a.y - ca.y, v2 = a.z - ca.z, v3 = a.w - ca.w;
            float v4 = b.x - cb2.x, v5 = b.y - cb2.y, v6 = b.z - cb2.z, v7 = b.w - cb2.w;
            rp4[2*k]   = float4{v0, v1, v2, v3};
            rp4[2*k+1] = float4{v4, v5, v6, v7};
            bf16x8 o;
            o[0]=f2bf(v0); o[1]=f2bf(v1); o[2]=f2bf(v2); o[3]=f2bf(v3);
            o[4]=f2bf(v4); o[5]=f2bf(v5); o[6]=f2bf(v6); o[7]=f2bf(v7);
            *(bf16x8*)(rb + 8*k) = o;
            if (k == 0) {
                r8[0]=v0*v0; r8[1]=v1*v1; r8[2]=v2*v2; r8[3]=v3*v3;
                r8[4]=v4*v4; r8[5]=v5*v5; r8[6]=v6*v6; r8[7]=v7*v7;
            } else {
                r8[0]=r8[0]+v0*v0; r8[1]=r8[1]+v1*v1; r8[2]=r8[2]+v2*v2; r8[3]=r8[3]+v3*v3;
                r8[4]=r8[4]+v4*v4; r8[5]=r8[5]+v5*v5; r8[6]=r8[6]+v6*v6; r8[7]=r8[7]+v7*v7;
            }
        }
        L = ((r8[0] + r8[1]) + (r8[2] + r8[3])) + ((r8[4] + r8[5]) + (r8[6] + r8[7]));
        Sp[(size_t)seg * N_ + n] = L;
    }
    double s = (double)L;
#pragma unroll
    for (int off = 32; off; off >>= 1) s += __shfl_down(s, off, 64);
    __shared__ double sred[4];
    int lane = threadIdx.x & 63, wv = threadIdx.x >> 6;
    if (lane == 0) sred[wv] = s;
    __syncthreads();
    if (threadIdx.x == 0)
        part[(size_t)q * SBLK_ + blockIdx.x] = sred[0] + sred[1] + sred[2] + sred[3];
}

// ---------------- outputs ----------------
__global__ __launch_bounds__(256) void k_out0T(const float* __restrict__ lat,
                                               const float* __restrict__ resT,
                                               float* __restrict__ out) {
    __shared__ float tile[32][33];   // [d][f]
    const int t = threadIdx.x;
    const int row = t >> 3, q4 = t & 7;
    for (int bi = blockIdx.x; bi < TILES_; bi += 1024) {
        int fb = bi % FB_, rem = bi / FB_;
        int db = rem & 15, b = rem >> 4;
        int f0 = fb * 32, d0 = db * 32;
        {
            int f = f0 + row;
            if (f < F_) {
                float4 v = *(const float4*)(resT + ((size_t)(b * F_ + f)) * D_ + d0 + 4 * q4);
                tile[4*q4+0][row] = v.x; tile[4*q4+1][row] = v.y;
                tile[4*q4+2][row] = v.z; tile[4*q4+3][row] = v.w;
            }
        }
        __syncthreads();
        {
            int fbase = f0 + 4 * q4;
            size_t o = ((size_t)b * D_ + d0 + row) * F_ + fbase;
            if (fbase + 3 < F_) {
                float4 lv = *(const float4*)(lat + o);
                float4 v;
                v.x = lv.x - tile[row][4*q4+0]; v.y = lv.y - tile[row][4*q4+1];
                v.z = lv.z - tile[row][4*q4+2]; v.w = lv.w - tile[row][4*q4+3];
                *(float4*)(out + o) = v;
            } else {
#pragma unroll
                for (int k = 0; k < 4; ++k)
                    if (fbase + k < F_) out[o + k] = lat[o + k] - tile[row][4*q4+k];
            }
        }
        __syncthreads();
    }
}

__global__ void k_codes(const int* __restrict__ codes, float* __restrict__ out1) {
    int bi = blockIdx.x;
    int q = bi & 7, b = bi >> 3;
    for (int f = threadIdx.x; f < F_; f += 256)
        out1[(size_t)bi * F_ + f] = (float)codes[(size_t)q * N_ + (size_t)b * F_ + f];
}

__global__ void k_loss(const double* __restrict__ part, float* __restrict__ out2) {
    double s = 0.0;
    for (int i = threadIdx.x; i < Q_ * SBLK_; i += 256) s += part[i];
#pragma unroll
    for (int off = 32; off; off >>= 1) s += __shfl_down(s, off, 64);
    __shared__ double red[4];
    int lane = threadIdx.x & 63, wv = threadIdx.x >> 6;
    if (lane == 0) red[wv] = s;
    __syncthreads();
    if (threadIdx.x == 0) {
        double tot = red[0] + red[1] + red[2] + red[3];
        float val = (float)(tot / ((double)Q_ * (double)B_ * (double)D_ * (double)F_));
        out2[0] = val;
        out2[1] = val;
    }
}

extern "C" void kernel_launch(void* const* d_in, const int* in_sizes, int n_in,
                              void* d_out, int out_size, void* d_ws, size_t ws_size,
                              hipStream_t stream) {
    const float* lat = (const float*)d_in[0];   // [16,512,1500] fp32
    const float* cb  = (const float*)d_in[1];   // [8,1024,512]  fp32
    char* ws = (char*)d_ws;
    float*  resT  = (float*)(ws);                 // 49,283,072
    short*  resbf = (short*)(ws + 49283072);      // 24,641,536
    short*  cbh   = (short*)(ws + 73924608);      //  8,388,608
    int*    codes = (int*)(ws + 82313216);        //    768,000
    float*  Hq    = (float*)(ws + 83081216);      //     32,768
    float*  Sp    = (float*)(ws + 83113984);      //    384,000
    double* part  = (double*)(ws + 83497984);     //     48,000
    float* out = (float*)d_out;

    hipLaunchKernelGGL(k_initT,    dim3(1024), dim3(256), 0, stream, lat, resT, resbf);
    hipLaunchKernelGGL(k_cbh,      dim3(512), dim3(256), 0, stream, cb, cbh);
    hipLaunchKernelGGL(k_cbnormP,  dim3(Q_ * C_ / 256), dim3(256), 0, stream, cb, Hq);
    hipLaunchKernelGGL(k_rownorm4, dim3(NBLK), dim3(256), 0, stream, resT, Sp);

    for (int q = 0; q < Q_; ++q) {
        hipLaunchKernelGGL(k_stage, dim3(SBLK_), dim3(256), 0, stream,
                           cbh, resT, resbf, cb, Hq, Sp, codes, part, q);
    }

    hipLaunchKernelGGL(k_out0T, dim3(1024), dim3(256), 0, stream, lat, resT, out);
    hipLaunchKernelGGL(k_codes, dim3(B_ * Q_), dim3(256), 0, stream, codes, out + 12288000);
    hipLaunchKernelGGL(k_loss,  dim3(1), dim3(256), 0, stream, part, out + 12480000);
}

// Round 16
// 1153.511 us; speedup vs baseline: 1.2842x; 1.2842x over previous
//
#include <hip/hip_runtime.h>
#include <hip/hip_fp16.h>

// ResidualVectorQuantizer: B=16, D=512, F=1500, Q=8, C=1024
#define B_ 16
#define D_ 512
#define F_ 1500
#define N_ (B_*F_)   // 24000
#define Q_ 8
#define C_ 1024

constexpr int NBLK  = (N_ + 255) / 256;   // 94
constexpr int FB_  = (F_ + 31) / 32;      // 47
constexpr int TILES_ = B_ * 16 * FB_;     // 12032
constexpr int SBLK_ = N_ / 64;            // 375 stage blocks

typedef __attribute__((ext_vector_type(8))) short bf16x8;
typedef __attribute__((ext_vector_type(4))) short bf16x4;
typedef __attribute__((ext_vector_type(4))) float f32x4;

__device__ __forceinline__ short f2bf(float f) {
    unsigned u = __float_as_uint(f);
    u += 0x7FFFu + ((u >> 16) & 1u);
    return (short)(u >> 16);
}
__device__ __forceinline__ float h2f(unsigned short u) {
    __half_raw r; r.x = u; return __half2float(__half(r));
}
__device__ __forceinline__ unsigned short f2h(float f) {
    __half h = __float2half(f);
    return __half_as_ushort(h);
}

// ---------------- init: resT/resbf[b*F+f][d] = lat[b][d][f], float4 both sides ----------------
__global__ __launch_bounds__(256) void k_initT(const float* __restrict__ lat,
                                               float* __restrict__ resT,
                                               short* __restrict__ resbf) {
    __shared__ float tile[32][33];   // [d][f]
    const int t = threadIdx.x;
    const int row = t >> 3, q4 = t & 7;
    for (int bi = blockIdx.x; bi < TILES_; bi += 1024) {
        int fb = bi % FB_, rem = bi / FB_;
        int db = rem & 15, b = rem >> 4;
        int f0 = fb * 32, d0 = db * 32;
        {
            int fbase = f0 + 4 * q4;
            const float* lp = lat + ((size_t)b * D_ + d0 + row) * F_ + fbase;
            if (fbase + 3 < F_) {
                float4 v = *(const float4*)lp;
                tile[row][4*q4+0] = v.x; tile[row][4*q4+1] = v.y;
                tile[row][4*q4+2] = v.z; tile[row][4*q4+3] = v.w;
            } else {
#pragma unroll
                for (int k = 0; k < 4; ++k)
                    tile[row][4*q4+k] = (fbase + k < F_) ? lp[k] : 0.0f;
            }
        }
        __syncthreads();
        {
            int f = f0 + row;
            if (f < F_) {
                float4 v;
                v.x = tile[4*q4+0][row]; v.y = tile[4*q4+1][row];
                v.z = tile[4*q4+2][row]; v.w = tile[4*q4+3][row];
                size_t o = ((size_t)(b * F_ + f)) * D_ + d0 + 4 * q4;
                *(float4*)(resT + o) = v;
                bf16x4 s;
                s[0] = f2bf(v.x); s[1] = f2bf(v.y); s[2] = f2bf(v.z); s[3] = f2bf(v.w);
                *(bf16x4*)(resbf + o) = s;
            }
        }
        __syncthreads();
    }
}

// ---------------- cbh = bf16(cb) ----------------
__global__ void k_cbh(const float* __restrict__ cb, short* __restrict__ cbh) {
    for (int g = blockIdx.x * 256 + threadIdx.x; g < Q_ * C_ * D_ / 8; g += 512 * 256) {
        size_t base = (size_t)g * 8;
        float4 a = *(const float4*)(cb + base);
        float4 b = *(const float4*)(cb + base + 4);
        bf16x8 o;
        o[0]=f2bf(a.x); o[1]=f2bf(a.y); o[2]=f2bf(a.z); o[3]=f2bf(a.w);
        o[4]=f2bf(b.x); o[5]=f2bf(b.y); o[6]=f2bf(b.z); o[7]=f2bf(b.w);
        *(bf16x8*)(cbh + base) = o;
    }
}

// ---------------- H[q*C+c] = np.sum(cb*cb, axis=1), numpy pairwise fp32 (verified) ----------------
__global__ void k_cbnormP(const float* __restrict__ cb, float* __restrict__ Hq) {
#pragma clang fp contract(off)
    int wid = blockIdx.x * 256 + threadIdx.x;
    const float* p = cb + (size_t)wid * D_;
    float L[4];
#pragma unroll
    for (int l = 0; l < 4; ++l) {
        const float* pl = p + l * 128;
        float r[8];
#pragma unroll
        for (int j = 0; j < 8; ++j) { float x = pl[j]; r[j] = x * x; }
        for (int i = 8; i < 128; i += 8) {
#pragma unroll
            for (int j = 0; j < 8; ++j) { float x = pl[i + j]; r[j] = r[j] + x * x; }
        }
        L[l] = ((r[0] + r[1]) + (r[2] + r[3])) + ((r[4] + r[5]) + (r[6] + r[7]));
    }
    Hq[wid] = (L[0] + L[1]) + (L[2] + L[3]);
}

// ---------------- initial S partials (verified chain) ----------------
__global__ void k_rownorm4(const float* __restrict__ resT, float* __restrict__ Sp) {
#pragma clang fp contract(off)
    int n = blockIdx.x * 256 + threadIdx.x;
    if (n >= N_) return;
#pragma unroll
    for (int l = 0; l < 4; ++l) {
        const float* p = resT + (size_t)n * D_ + l * 128;
        float r[8];
#pragma unroll
        for (int j = 0; j < 8; ++j) { float x = p[j]; r[j] = x * x; }
        for (int i = 8; i < 128; i += 8) {
#pragma unroll
            for (int j = 0; j < 8; ++j) { float x = p[i + j]; r[j] = r[j] + x * x; }
        }
        Sp[(size_t)l * N_ + n] = ((r[0] + r[1]) + (r[2] + r[3])) + ((r[4] + r[5]) + (r[6] + r[7]));
    }
}

// ---------------- fused stage: dbuf MFMA screen + collect + exact rescore + update ----------------
// block = 64 rows x all 1024 cols; 375 blocks; register double-buffered staging.
#define LSTR 80
__global__ __launch_bounds__(256) void k_stage(
        const short* __restrict__ cbh, float* __restrict__ resT,
        short* __restrict__ resbf, const float* __restrict__ cb,
        const float* __restrict__ Hq, float* __restrict__ Sp,
        int* __restrict__ codes, double* __restrict__ part, int q) {
#pragma clang fp contract(off)
    __shared__ short xh[64 * LSTR];
    __shared__ short ch[128 * LSTR];
    __shared__ float smin[64][2];
    __shared__ float bminG[64];
    __shared__ unsigned lcnt[64];
    __shared__ unsigned slots[64][16];
    __shared__ unsigned witems[1024];
    __shared__ unsigned long long rkeyL[64];
    __shared__ int fbrows[64];
    __shared__ int codeL[64];
    __shared__ unsigned wcnt_s, fbcnt_s;

    const int t = threadIdx.x, l = t & 63, w = t >> 6;
    const int wr = w >> 1, wc = w & 1;
    const int n0 = blockIdx.x * 64;
    const int nn = t >> 3, d8 = t & 7;
    const short* cbhq = cbh + (size_t)q * C_ * D_;
    const float* Hqq = Hq + (size_t)q * C_;
    const float* cbq = cb + (size_t)q * ((size_t)C_ * D_);

    if (t < 64) { bminG[t] = 3.4e38f; lcnt[t] = 0; rkeyL[t] = ~0ull; }
    if (t == 0) { wcnt_s = 0; fbcnt_s = 0; }

    // register double-buffer staging
    bf16x8 rxa, rxb, rc[4];
    {   // prefetch (c0=0, kc=0)
        rxa = *(const bf16x8*)(resbf + (size_t)(n0 + nn) * D_ + d8 * 8);
        rxb = *(const bf16x8*)(resbf + (size_t)(n0 + 32 + nn) * D_ + d8 * 8);
#pragma unroll
        for (int p = 0; p < 4; ++p)
            rc[p] = *(const bf16x8*)(cbhq + (size_t)(32 * p + nn) * D_ + d8 * 8);
    }

    for (int c0 = 0; c0 < C_; c0 += 128) {
        f32x4 acc[2][4];
#pragma unroll
        for (int i = 0; i < 2; ++i)
#pragma unroll
            for (int j = 0; j < 4; ++j) { acc[i][j][0]=0.f; acc[i][j][1]=0.f; acc[i][j][2]=0.f; acc[i][j][3]=0.f; }

        for (int kc = 0; kc < D_; kc += 64) {
            __syncthreads();
            *(bf16x8*)(&xh[nn * LSTR + d8 * 8]) = rxa;
            *(bf16x8*)(&xh[(32 + nn) * LSTR + d8 * 8]) = rxb;
#pragma unroll
            for (int p = 0; p < 4; ++p)
                *(bf16x8*)(&ch[(32 * p + nn) * LSTR + d8 * 8]) = rc[p];
            __syncthreads();

            {   // prefetch next tile (hidden under MFMA phase)
                int nkc = kc + 64, nc0 = c0;
                if (nkc == D_) { nkc = 0; nc0 = c0 + 128; }
                if (nc0 < C_) {
                    rxa = *(const bf16x8*)(resbf + (size_t)(n0 + nn) * D_ + nkc + d8 * 8);
                    rxb = *(const bf16x8*)(resbf + (size_t)(n0 + 32 + nn) * D_ + nkc + d8 * 8);
#pragma unroll
                    for (int p = 0; p < 4; ++p)
                        rc[p] = *(const bf16x8*)(cbhq + (size_t)(nc0 + 32 * p + nn) * D_ + nkc + d8 * 8);
                }
            }

#pragma unroll
            for (int kf = 0; kf < 2; ++kf) {
                const int ko = kf * 32 + (l >> 4) * 8;
                bf16x8 ah[2], bh[4];
#pragma unroll
                for (int i = 0; i < 2; ++i)
                    ah[i] = *(const bf16x8*)(&xh[(wr * 32 + i * 16 + (l & 15)) * LSTR + ko]);
#pragma unroll
                for (int j = 0; j < 4; ++j)
                    bh[j] = *(const bf16x8*)(&ch[(wc * 64 + j * 16 + (l & 15)) * LSTR + ko]);
#pragma unroll
                for (int i = 0; i < 2; ++i)
#pragma unroll
                    for (int j = 0; j < 4; ++j)
                        acc[i][j] = __builtin_amdgcn_mfma_f32_16x16x32_bf16(ah[i], bh[j], acc[i][j], 0, 0, 0);
            }
        }

        float hv[4];
#pragma unroll
        for (int j = 0; j < 4; ++j) hv[j] = Hqq[c0 + wc * 64 + j * 16 + (l & 15)];

        // strip row minima
#pragma unroll
        for (int i = 0; i < 2; ++i)
#pragma unroll
            for (int r = 0; r < 4; ++r) {
                float vm = hv[0] - 2.0f * acc[i][0][r];
#pragma unroll
                for (int j = 1; j < 4; ++j) vm = fminf(vm, hv[j] - 2.0f * acc[i][j][r]);
                vm = fminf(vm, __shfl_xor(vm, 1, 64));
                vm = fminf(vm, __shfl_xor(vm, 2, 64));
                vm = fminf(vm, __shfl_xor(vm, 4, 64));
                vm = fminf(vm, __shfl_xor(vm, 8, 64));
                if ((l & 15) == 0) smin[wr * 32 + i * 16 + (l >> 4) * 4 + r][wc] = vm;
            }
        __syncthreads();
        if (t < 64) bminG[t] = fminf(bminG[t], fminf(smin[t][0], smin[t][1]));
        __syncthreads();
        // emit candidates within running-min + 1.6e-3 (superset of decision set)
#pragma unroll
        for (int i = 0; i < 2; ++i)
#pragma unroll
            for (int j = 0; j < 4; ++j)
#pragma unroll
                for (int r = 0; r < 4; ++r) {
                    int row = wr * 32 + i * 16 + (l >> 4) * 4 + r;
                    float v = hv[j] - 2.0f * acc[i][j][r];
                    if (v <= bminG[row] + 1.6e-3f) {
                        unsigned pos = atomicAdd(&lcnt[row], 1u);
                        if (pos < 16) {
                            unsigned c = (unsigned)(c0 + wc * 64 + j * 16 + (l & 15));
                            slots[row][pos] = ((unsigned)f2h(v) << 16) | c;
                        }
                    }
                }
    }
    __syncthreads();

    // finalize rows
    if (t < 64) {
        float thr = bminG[t] + 1.5e-3f;
        unsigned lc = lcnt[t];
        if (lc > 16u) {
            unsigned fp = atomicAdd(&fbcnt_s, 1u);
            fbrows[fp] = t;
        } else {
            int cnt = 0, c1 = -1;
            for (unsigned s = 0; s < lc; ++s) {
                unsigned e = slots[t][s];
                if (h2f((unsigned short)(e >> 16)) <= thr) { ++cnt; if (cnt == 1) c1 = (int)(e & 0x3FFu); }
            }
            if (cnt == 1) {
                codeL[t] = c1;
            } else {
                codeL[t] = -1;
                for (unsigned s = 0; s < lc; ++s) {
                    unsigned e = slots[t][s];
                    if (h2f((unsigned short)(e >> 16)) <= thr) {
                        unsigned pos = atomicAdd(&wcnt_s, 1u);
                        witems[pos] = ((unsigned)t << 10) | (e & 0x3FFu);
                    }
                }
            }
        }
    }
    __syncthreads();

    // dense exact-chain rescore (verified chain + lex tie)
    {
        unsigned wn = wcnt_s;
        for (unsigned i = t; i < wn; i += 256) {
            unsigned e = witems[i];
            int lr = (int)(e >> 10), c = (int)(e & 0x3FFu);
            int n = n0 + lr;
            float S = (Sp[n] + Sp[N_ + n]) + (Sp[2 * N_ + n] + Sp[3 * N_ + n]);
            const float* xr = resT + (size_t)n * D_;
            const float* cr = cbq + (size_t)c * D_;
            float A = 0.0f;
#pragma unroll 8
            for (int d = 0; d < D_; ++d) A = fmaf(xr[d], cr[d], A);
            float v = (S - 2.0f * A) + Hqq[c];
            unsigned long long key = ((unsigned long long)__float_as_uint(v) << 32) | (unsigned)c;
            atomicMin(&rkeyL[lr], key);
        }
    }
    __syncthreads();
    if (t < 64 && codeL[t] < 0) codeL[t] = (int)(rkeyL[t] & 0x3FFull);

    // rare full-row fallback (wave per row)
    {
        unsigned fn = fbcnt_s;
        for (unsigned fi = w; fi < fn; fi += 4) {
            int lr = fbrows[fi];
            int n = n0 + lr;
            float S = (Sp[n] + Sp[N_ + n]) + (Sp[2 * N_ + n] + Sp[3 * N_ + n]);
            const float4* xr4 = (const float4*)(resT + (size_t)n * D_);
            float mn = 3.4e38f;
            for (int rep = 0; rep < 16; ++rep) {
                int c = l + rep * 64;
                const float4* cr4 = (const float4*)(cbq + (size_t)c * D_);
                float a0 = 0.f, a1 = 0.f, a2 = 0.f, a3 = 0.f;
#pragma unroll 4
                for (int d4 = 0; d4 < 128; ++d4) {
                    float4 xv = xr4[d4], cv = cr4[d4];
                    a0 = fmaf(xv.x, cv.x, a0); a1 = fmaf(xv.y, cv.y, a1);
                    a2 = fmaf(xv.z, cv.z, a2); a3 = fmaf(xv.w, cv.w, a3);
                }
                float v = (S - 2.0f * ((a0 + a1) + (a2 + a3))) + Hqq[c];
                mn = fminf(mn, v);
            }
            for (int off = 32; off; off >>= 1) mn = fminf(mn, __shfl_xor(mn, off, 64));
            const float thr2 = mn + 6e-4f;
            float bv = 3.4e38f; int bc = 0x7fffffff;
            const float* xr = resT + (size_t)n * D_;
            for (int rep = 0; rep < 16; ++rep) {
                int c = l + rep * 64;
                const float4* cr4 = (const float4*)(cbq + (size_t)c * D_);
                float a0 = 0.f, a1 = 0.f, a2 = 0.f, a3 = 0.f;
#pragma unroll 4
                for (int d4 = 0; d4 < 128; ++d4) {
                    float4 xv = xr4[d4], cv = cr4[d4];
                    a0 = fmaf(xv.x, cv.x, a0); a1 = fmaf(xv.y, cv.y, a1);
                    a2 = fmaf(xv.z, cv.z, a2); a3 = fmaf(xv.w, cv.w, a3);
                }
                float vap = (S - 2.0f * ((a0 + a1) + (a2 + a3))) + Hqq[c];
                if (vap <= thr2) {
                    const float* cr = cbq + (size_t)c * D_;
                    float A = 0.0f;
#pragma unroll 8
                    for (int d = 0; d < D_; ++d) A = fmaf(xr[d], cr[d], A);
                    float v = (S - 2.0f * A) + Hqq[c];
                    if (v < bv || (v == bv && c < bc)) { bv = v; bc = c; }
                }
            }
            for (int off = 32; off; off >>= 1) {
                float ov = __shfl_xor(bv, off, 64);
                int oc = __shfl_xor(bc, off, 64);
                if (ov < bv || (ov == bv && oc < bc)) { bv = ov; bc = oc; }
            }
            if (l == 0) codeL[lr] = bc;
        }
    }
    __syncthreads();
    if (t < 64) codes[(size_t)q * N_ + n0 + t] = codeL[t];

    // ---- fused residual update (verified chain), 64 rows x 4 segs = 256 threads ----
    float L = 0.0f;
    {
        int lr = t >> 2, seg = t & 3;
        int n = n0 + lr;
        int idx = codeL[lr];
        const float4* cr4 = (const float4*)(cb + ((size_t)q * C_ + idx) * D_ + seg * 128);
        float4* rp4 = (float4*)(resT + (size_t)n * D_ + seg * 128);
        short* rb = resbf + (size_t)n * D_ + seg * 128;
        float r8[8];
#pragma unroll
        for (int k = 0; k < 16; ++k) {
            float4 a = rp4[2*k], b = rp4[2*k+1];
            float4 ca = cr4[2*k], cb2 = cr4[2*k+1];
            float v0 = a.x - ca.x, v1 = a.y - ca.y, v2 = a.z - ca.z, v3 = a.w - ca.w;
            float v4 = b.x - cb2.x, v5 = b.y - cb2.y, v6 = b.z - cb2.z, v7 = b.w - cb2.w;
            rp4[2*k]   = float4{v0, v1, v2, v3};
            rp4[2*k+1] = float4{v4, v5, v6, v7};
            bf16x8 o;
            o[0]=f2bf(v0); o[1]=f2bf(v1); o[2]=f2bf(v2); o[3]=f2bf(v3);
            o[4]=f2bf(v4); o[5]=f2bf(v5); o[6]=f2bf(v6); o[7]=f2bf(v7);
            *(bf16x8*)(rb + 8*k) = o;
            if (k == 0) {
                r8[0]=v0*v0; r8[1]=v1*v1; r8[2]=v2*v2; r8[3]=v3*v3;
                r8[4]=v4*v4; r8[5]=v5*v5; r8[6]=v6*v6; r8[7]=v7*v7;
            } else {
                r8[0]=r8[0]+v0*v0; r8[1]=r8[1]+v1*v1; r8[2]=r8[2]+v2*v2; r8[3]=r8[3]+v3*v3;
                r8[4]=r8[4]+v4*v4; r8[5]=r8[5]+v5*v5; r8[6]=r8[6]+v6*v6; r8[7]=r8[7]+v7*v7;
            }
        }
        L = ((r8[0] + r8[1]) + (r8[2] + r8[3])) + ((r8[4] + r8[5]) + (r8[6] + r8[7]));
        Sp[(size_t)seg * N_ + n] = L;
    }
    double s = (double)L;
#pragma unroll
    for (int off = 32; off; off >>= 1) s += __shfl_down(s, off, 64);
    __shared__ double sred[4];
    int lane = threadIdx.x & 63, wv = threadIdx.x >> 6;
    if (lane == 0) sred[wv] = s;
    __syncthreads();
    if (threadIdx.x == 0)
        part[(size_t)q * SBLK_ + blockIdx.x] = sred[0] + sred[1] + sred[2] + sred[3];
}

// ---------------- outputs ----------------
__global__ __launch_bounds__(256) void k_out0T(const float* __restrict__ lat,
                                               const float* __restrict__ resT,
                                               float* __restrict__ out) {
    __shared__ float tile[32][33];   // [d][f]
    const int t = threadIdx.x;
    const int row = t >> 3, q4 = t & 7;
    for (int bi = blockIdx.x; bi < TILES_; bi += 1024) {
        int fb = bi % FB_, rem = bi / FB_;
        int db = rem & 15, b = rem >> 4;
        int f0 = fb * 32, d0 = db * 32;
        {
            int f = f0 + row;
            if (f < F_) {
                float4 v = *(const float4*)(resT + ((size_t)(b * F_ + f)) * D_ + d0 + 4 * q4);
                tile[4*q4+0][row] = v.x; tile[4*q4+1][row] = v.y;
                tile[4*q4+2][row] = v.z; tile[4*q4+3][row] = v.w;
            }
        }
        __syncthreads();
        {
            int fbase = f0 + 4 * q4;
            size_t o = ((size_t)b * D_ + d0 + row) * F_ + fbase;
            if (fbase + 3 < F_) {
                float4 lv = *(const float4*)(lat + o);
                float4 v;
                v.x = lv.x - tile[row][4*q4+0]; v.y = lv.y - tile[row][4*q4+1];
                v.z = lv.z - tile[row][4*q4+2]; v.w = lv.w - tile[row][4*q4+3];
                *(float4*)(out + o) = v;
            } else {
#pragma unroll
                for (int k = 0; k < 4; ++k)
                    if (fbase + k < F_) out[o + k] = lat[o + k] - tile[row][4*q4+k];
            }
        }
        __syncthreads();
    }
}

__global__ void k_codes(const int* __restrict__ codes, float* __restrict__ out1) {
    int bi = blockIdx.x;
    int q = bi & 7, b = bi >> 3;
    for (int f = threadIdx.x; f < F_; f += 256)
        out1[(size_t)bi * F_ + f] = (float)codes[(size_t)q * N_ + (size_t)b * F_ + f];
}

__global__ void k_loss(const double* __restrict__ part, float* __restrict__ out2) {
    double s = 0.0;
    for (int i = threadIdx.x; i < Q_ * SBLK_; i += 256) s += part[i];
#pragma unroll
    for (int off = 32; off; off >>= 1) s += __shfl_down(s, off, 64);
    __shared__ double red[4];
    int lane = threadIdx.x & 63, wv = threadIdx.x >> 6;
    if (lane == 0) red[wv] = s;
    __syncthreads();
    if (threadIdx.x == 0) {
        double tot = red[0] + red[1] + red[2] + red[3];
        float val = (float)(tot / ((double)Q_ * (double)B_ * (double)D_ * (double)F_));
        out2[0] = val;
        out2[1] = val;
    }
}

extern "C" void kernel_launch(void* const* d_in, const int* in_sizes, int n_in,
                              void* d_out, int out_size, void* d_ws, size_t ws_size,
                              hipStream_t stream) {
    const float* lat = (const float*)d_in[0];   // [16,512,1500] fp32
    const float* cb  = (const float*)d_in[1];   // [8,1024,512]  fp32
    char* ws = (char*)d_ws;
    float*  resT  = (float*)(ws);                 // 49,283,072
    short*  resbf = (short*)(ws + 49283072);      // 24,641,536
    short*  cbh   = (short*)(ws + 73924608);      //  8,388,608
    int*    codes = (int*)(ws + 82313216);        //    768,000
    float*  Hq    = (float*)(ws + 83081216);      //     32,768
    float*  Sp    = (float*)(ws + 83113984);      //    384,000
    double* part  = (double*)(ws + 83497984);     //     24,000
    float* out = (float*)d_out;

    hipLaunchKernelGGL(k_initT,    dim3(1024), dim3(256), 0, stream, lat, resT, resbf);
    hipLaunchKernelGGL(k_cbh,      dim3(512), dim3(256), 0, stream, cb, cbh);
    hipLaunchKernelGGL(k_cbnormP,  dim3(Q_ * C_ / 256), dim3(256), 0, stream, cb, Hq);
    hipLaunchKernelGGL(k_rownorm4, dim3(NBLK), dim3(256), 0, stream, resT, Sp);

    for (int q = 0; q < Q_; ++q) {
        hipLaunchKernelGGL(k_stage, dim3(SBLK_), dim3(256), 0, stream,
                           cbh, resT, resbf, cb, Hq, Sp, codes, part, q);
    }

    hipLaunchKernelGGL(k_out0T, dim3(1024), dim3(256), 0, stream, lat, resT, out);
    hipLaunchKernelGGL(k_codes, dim3(B_ * Q_), dim3(256), 0, stream, codes, out + 12288000);
    hipLaunchKernelGGL(k_loss,  dim3(1), dim3(256), 0, stream, part, out + 12480000);
}